// Round 6
// baseline (128.300 us; speedup 1.0000x reference)
//
#include <hip/hip_runtime.h>

#define B_ 16
#define QN 256
#define KN 256
#define DN 256
#define HN 256

#define LOG2E 1.4426950408889634f
#define TWOLOG2E 2.8853900817779268f  // exp2(x*this) = e^{2x}

// ---------------- Kernel A (fused): projections ----------------
// 16 rows/block; thread owns 4 rows x 4 h (wave = one 4-row group -> x reads are
// wave-uniform LDS broadcasts, 4 FMA per LDS b128 per row => FMA-bound, not LDS-bound).
// First half of grid: qs[b][q][h] row-major. Second half: ksT[b][h][k] transposed
// (thread holds 4 consecutive k per h -> direct float4 stores).
__global__ __launch_bounds__(256) void proj_kernel(const float* __restrict__ Xq,
                                                   const float* __restrict__ Xk,
                                                   const float* __restrict__ Wq,
                                                   const float* __restrict__ Wk,
                                                   float* __restrict__ Yq,
                                                   float* __restrict__ YkT,
                                                   float scale) {
    const int nb = (int)gridDim.x >> 1;
    int blk = blockIdx.x;
    const bool is_q = blk < nb;
    const float* X;
    const float* W;
    if (is_q) { X = Xq; W = Wq; }
    else      { X = Xk; W = Wk; blk -= nb; }
    const int row0 = blk * 16;

    __shared__ float xl[16][DN];   // 16 KB
    const int tid = threadIdx.x;

    {
        const float4* src = (const float4*)(X + (size_t)row0 * DN);
        float4* dst = (float4*)&xl[0][0];
#pragma unroll
        for (int i = 0; i < 4; ++i) dst[tid + 256 * i] = src[tid + 256 * i];
    }
    __syncthreads();

    const int rg = tid >> 6;          // wave id: rows rg*4 .. rg*4+3
    const int hg = tid & 63;          // h = 4*hg .. 4*hg+3
    const int h4 = hg << 2;

    float4 acc[4];
#pragma unroll
    for (int r = 0; r < 4; ++r) acc[r] = make_float4(0.f, 0.f, 0.f, 0.f);

    for (int d0 = 0; d0 < DN; d0 += 4) {
        float4 w[4];
#pragma unroll
        for (int j = 0; j < 4; ++j)
            w[j] = *(const float4*)&W[(size_t)(d0 + j) * HN + h4];  // coalesced b128
        float4 x[4];
#pragma unroll
        for (int r = 0; r < 4; ++r)
            x[r] = *(const float4*)&xl[(rg << 2) + r][d0];          // wave-broadcast
#pragma unroll
        for (int r = 0; r < 4; ++r) {
            acc[r].x = fmaf(x[r].x, w[0].x, acc[r].x);
            acc[r].y = fmaf(x[r].x, w[0].y, acc[r].y);
            acc[r].z = fmaf(x[r].x, w[0].z, acc[r].z);
            acc[r].w = fmaf(x[r].x, w[0].w, acc[r].w);
            acc[r].x = fmaf(x[r].y, w[1].x, acc[r].x);
            acc[r].y = fmaf(x[r].y, w[1].y, acc[r].y);
            acc[r].z = fmaf(x[r].y, w[1].z, acc[r].z);
            acc[r].w = fmaf(x[r].y, w[1].w, acc[r].w);
            acc[r].x = fmaf(x[r].z, w[2].x, acc[r].x);
            acc[r].y = fmaf(x[r].z, w[2].y, acc[r].y);
            acc[r].z = fmaf(x[r].z, w[2].z, acc[r].z);
            acc[r].w = fmaf(x[r].z, w[2].w, acc[r].w);
            acc[r].x = fmaf(x[r].w, w[3].x, acc[r].x);
            acc[r].y = fmaf(x[r].w, w[3].y, acc[r].y);
            acc[r].z = fmaf(x[r].w, w[3].z, acc[r].z);
            acc[r].w = fmaf(x[r].w, w[3].w, acc[r].w);
        }
    }

    if (is_q) {
#pragma unroll
        for (int r = 0; r < 4; ++r) {
            float4 o = make_float4(acc[r].x * scale, acc[r].y * scale,
                                   acc[r].z * scale, acc[r].w * scale);
            *(float4*)&Yq[(size_t)(row0 + (rg << 2) + r) * HN + h4] = o;
        }
    } else {
        const int b = row0 >> 8, kloc = (row0 & 255) + (rg << 2);
#pragma unroll
        for (int j = 0; j < 4; ++j) {
            // h = h4+j, k = kloc..kloc+3 ; acc[r][j] is (k=kloc+r, h=h4+j)
            float4 o;
            o.x = acc[0].x * scale; // placeholder overwritten below per component
            float vals[4] = {acc[0].x, acc[1].x, acc[2].x, acc[3].x};
            if (j == 1) { vals[0] = acc[0].y; vals[1] = acc[1].y; vals[2] = acc[2].y; vals[3] = acc[3].y; }
            if (j == 2) { vals[0] = acc[0].z; vals[1] = acc[1].z; vals[2] = acc[2].z; vals[3] = acc[3].z; }
            if (j == 3) { vals[0] = acc[0].w; vals[1] = acc[1].w; vals[2] = acc[2].w; vals[3] = acc[3].w; }
            o = make_float4(vals[0] * scale, vals[1] * scale, vals[2] * scale, vals[3] * scale);
            *(float4*)&YkT[((size_t)b * HN + h4 + j) * KN + kloc] = o;
        }
    }
}

// ------------- Kernel B: ACC[b][q][k] = sum_h wv[h] * rcp(1 + exp2(qs+ksT)) ----------
// true score = Wsum - 2*ACC; Wsum constant per q-row -> softmax-invariant, never formed.
// Block = 1024 threads: 4 h-chunks x (16q x 64k) tile. Each 256-thread sub-block runs
// the no-LDS inner loop over its 64-h chunk; 12 KB LDS combine at the end.
// 2 blocks/CU = 32 waves/CU resident -> load latency hidden.
__global__ __launch_bounds__(1024, 2) void score_kernel(const float* __restrict__ QS,
                                                        const float* __restrict__ KT,
                                                        const float* __restrict__ wv,
                                                        const int* __restrict__ lens,
                                                        float* __restrict__ ACC) {
    const int b = blockIdx.z;
    const int k0 = blockIdx.x * 64;
    const int q0 = blockIdx.y * 16;
    const int len = lens[b];
    if (k0 >= len) return;  // whole tile masked -> never read downstream

    const int tid = threadIdx.x;
    const int t = tid & 255;
    const int hc = tid >> 8;    // h-chunk 0..3
    const int q = t >> 4;       // 0..15
    const int kg = t & 15;      // owns k = k0 + 4*kg .. +3

    const float* qrow = QS + ((size_t)b * QN + q0 + q) * HN;
    const float* kt = KT + (size_t)b * HN * KN + k0 + (kg << 2);

    float acc0 = 0.f, acc1 = 0.f, acc2 = 0.f, acc3 = 0.f;
    const int hbeg = hc << 6;

#pragma unroll 2
    for (int h0 = hbeg; h0 < hbeg + 64; h0 += 8) {
        float4 kv[8];
#pragma unroll
        for (int u = 0; u < 8; ++u)
            kv[u] = *(const float4*)&kt[(size_t)(h0 + u) * KN];
        float4 qa = *(const float4*)&qrow[h0];
        float4 qb = *(const float4*)&qrow[h0 + 4];
        float4 wa = *(const float4*)&wv[h0];
        float4 wb = *(const float4*)&wv[h0 + 4];
        float qv[8] = {qa.x, qa.y, qa.z, qa.w, qb.x, qb.y, qb.z, qb.w};
        float wl[8] = {wa.x, wa.y, wa.z, wa.w, wb.x, wb.y, wb.z, wb.w};
#pragma unroll
        for (int u = 0; u < 8; ++u) {
            float e0 = __builtin_amdgcn_exp2f(qv[u] + kv[u].x);
            float e1 = __builtin_amdgcn_exp2f(qv[u] + kv[u].y);
            float e2 = __builtin_amdgcn_exp2f(qv[u] + kv[u].z);
            float e3 = __builtin_amdgcn_exp2f(qv[u] + kv[u].w);
            acc0 = fmaf(wl[u], __builtin_amdgcn_rcpf(1.f + e0), acc0);
            acc1 = fmaf(wl[u], __builtin_amdgcn_rcpf(1.f + e1), acc1);
            acc2 = fmaf(wl[u], __builtin_amdgcn_rcpf(1.f + e2), acc2);
            acc3 = fmaf(wl[u], __builtin_amdgcn_rcpf(1.f + e3), acc3);
        }
    }

    __shared__ float4 part[3][256];  // 12 KB
    if (hc) part[hc - 1][t] = make_float4(acc0, acc1, acc2, acc3);
    __syncthreads();
    if (hc == 0) {
#pragma unroll
        for (int j = 0; j < 3; ++j) {
            float4 p = part[j][t];
            acc0 += p.x; acc1 += p.y; acc2 += p.z; acc3 += p.w;
        }
        *(float4*)&ACC[((size_t)b * QN + q0 + q) * KN + k0 + (kg << 2)] =
            make_float4(acc0, acc1, acc2, acc3);
    }
}

// ------------- Kernel C: masked softmax over (-2*ACC) then attn @ values -------------
__global__ __launch_bounds__(256) void softmax_pv_kernel(const float* __restrict__ ACC,
                                                         const float* __restrict__ V,
                                                         const int* __restrict__ lens,
                                                         float* __restrict__ OUT) {
    const int b = blockIdx.y;
    const int q0 = blockIdx.x * 8;
    const int len = lens[b];

    __shared__ float sl[8][256];
    const int tid = threadIdx.x;

    const float* src = ACC + ((size_t)b * QN + q0) * KN;
#pragma unroll
    for (int i = tid; i < 8 * 256; i += 256) {
        int r = i >> 8, k = i & 255;
        float v = src[r * KN + k];
        sl[r][k] = (k < len) ? (-2.f * v) : -1e6f;
    }
    __syncthreads();

    const int wave = tid >> 6, lane = tid & 63;
    for (int r = wave; r < 8; r += 4) {
        float x0 = sl[r][lane];
        float x1 = sl[r][lane + 64];
        float x2 = sl[r][lane + 128];
        float x3 = sl[r][lane + 192];
        float m = fmaxf(fmaxf(x0, x1), fmaxf(x2, x3));
#pragma unroll
        for (int off = 32; off; off >>= 1) m = fmaxf(m, __shfl_xor(m, off, 64));
        float p0 = __builtin_amdgcn_exp2f((x0 - m) * LOG2E);
        float p1 = __builtin_amdgcn_exp2f((x1 - m) * LOG2E);
        float p2 = __builtin_amdgcn_exp2f((x2 - m) * LOG2E);
        float p3 = __builtin_amdgcn_exp2f((x3 - m) * LOG2E);
        float s = (p0 + p1) + (p2 + p3);
#pragma unroll
        for (int off = 32; off; off >>= 1) s += __shfl_xor(s, off, 64);
        float inv = 1.f / s;
        sl[r][lane] = p0 * inv;
        sl[r][lane + 64] = p1 * inv;
        sl[r][lane + 128] = p2 * inv;
        sl[r][lane + 192] = p3 * inv;
    }
    __syncthreads();

    const int d = tid;
    float out_acc[8];
#pragma unroll
    for (int r = 0; r < 8; ++r) out_acc[r] = 0.f;

    const float* vbase = V + (size_t)b * KN * DN + d;
    const int len4 = (len + 3) & ~3;
    for (int k = 0; k < len4; k += 4) {
        float v0 = vbase[(size_t)(k + 0) * DN];
        float v1 = vbase[(size_t)(k + 1) * DN];
        float v2 = vbase[(size_t)(k + 2) * DN];
        float v3 = vbase[(size_t)(k + 3) * DN];
#pragma unroll
        for (int r = 0; r < 8; ++r) {
            float4 a = *(const float4*)&sl[r][k];
            out_acc[r] = fmaf(a.x, v0, out_acc[r]);
            out_acc[r] = fmaf(a.y, v1, out_acc[r]);
            out_acc[r] = fmaf(a.z, v2, out_acc[r]);
            out_acc[r] = fmaf(a.w, v3, out_acc[r]);
        }
    }
    float* obase = OUT + ((size_t)b * QN + q0) * DN + d;
#pragma unroll
    for (int r = 0; r < 8; ++r) obase[(size_t)r * DN] = out_acc[r];
}

extern "C" void kernel_launch(void* const* d_in, const int* in_sizes, int n_in,
                              void* d_out, int out_size, void* d_ws, size_t ws_size,
                              hipStream_t stream) {
    const float* queries = (const float*)d_in[0];
    const float* keys    = (const float*)d_in[1];
    const float* values  = (const float*)d_in[2];
    const int*   lens    = (const int*)d_in[3];
    const float* Wq      = (const float*)d_in[4];
    const float* Wk      = (const float*)d_in[5];
    const float* wv      = (const float*)d_in[6];
    float* out = (float*)d_out;

    float* qs  = (float*)d_ws;                       // [B,Q,H]  4 MB (row-major)
    float* ksT = qs + (size_t)B_ * QN * HN;          // [B,H,K]  4 MB (transposed)
    float* acc = ksT + (size_t)B_ * HN * KN;         // [B,Q,K]  4 MB

    proj_kernel<<<(B_ * QN + B_ * KN) / 16, 256, 0, stream>>>(
        queries, keys, Wq, Wk, qs, ksT, TWOLOG2E);

    dim3 gB(KN / 64, QN / 16, B_);
    score_kernel<<<gB, 1024, 0, stream>>>(qs, ksT, wv, lens, acc);

    dim3 gC(QN / 8, B_);
    softmax_pv_kernel<<<gC, 256, 0, stream>>>(acc, values, lens, out);
}

// Round 7
// 85.468 us; speedup vs baseline: 1.5011x; 1.5011x over previous
//
#include <hip/hip_runtime.h>

#define B_ 16
#define QN 256
#define KN 256
#define DN 256
#define HN 256

#define LOG2E 1.4426950408889634f
#define TWOLOG2E 2.8853900817779268f  // exp2(x*this) = e^{2x}

// ---------------- Kernel A (fused): projections ----------------
// 16 rows/block, thread = h, acc[16] over rows (R3 structure, best measured).
// First half of grid: qs[b][q][h] = (queries@Wq)*scale, row-major direct stores.
// Second half: ksT[b][h][k] = (keys@Wk)*scale via LDS transpose so global stores are
// 64B-segmented (4 segs/wave) instead of 64 x 1KB-strided lanes.
__global__ __launch_bounds__(256) void proj_kernel(const float* __restrict__ Xq,
                                                   const float* __restrict__ Xk,
                                                   const float* __restrict__ Wq,
                                                   const float* __restrict__ Wk,
                                                   float* __restrict__ Yq,
                                                   float* __restrict__ YkT,
                                                   float scale) {
    const int nb = (int)gridDim.x >> 1;
    int blk = blockIdx.x;
    const bool is_q = blk < nb;
    const float* X;
    const float* W;
    if (is_q) { X = Xq; W = Wq; }
    else      { X = Xk; W = Wk; blk -= nb; }
    const int row0 = blk * 16;

    __shared__ float xl[16][DN];        // 16 KB
    __shared__ float trans[16][257];    // 16.4 KB (keys path transpose; +1 pad)
    const int tid = threadIdx.x;

    {
        const float4* src = (const float4*)(X + (size_t)row0 * DN);
        float4* dst = (float4*)&xl[0][0];
#pragma unroll
        for (int i = 0; i < 4; ++i) dst[tid + 256 * i] = src[tid + 256 * i];
    }
    __syncthreads();

    const int h = tid;
    float acc[16];
#pragma unroll
    for (int r = 0; r < 16; ++r) acc[r] = 0.f;

    for (int d0 = 0; d0 < DN; d0 += 4) {
        float w0 = W[(size_t)(d0 + 0) * HN + h];
        float w1 = W[(size_t)(d0 + 1) * HN + h];
        float w2 = W[(size_t)(d0 + 2) * HN + h];
        float w3 = W[(size_t)(d0 + 3) * HN + h];
#pragma unroll
        for (int r = 0; r < 16; ++r) {
            float4 x = *(const float4*)&xl[r][d0];  // wave-uniform -> LDS broadcast
            acc[r] = fmaf(x.x, w0, acc[r]);
            acc[r] = fmaf(x.y, w1, acc[r]);
            acc[r] = fmaf(x.z, w2, acc[r]);
            acc[r] = fmaf(x.w, w3, acc[r]);
        }
    }

    if (is_q) {
#pragma unroll
        for (int r = 0; r < 16; ++r)
            Yq[(size_t)(row0 + r) * HN + h] = acc[r] * scale;
    } else {
        // transpose through LDS: trans[k_local][h] = acc[k_local]*scale
#pragma unroll
        for (int r = 0; r < 16; ++r) trans[r][h] = acc[r] * scale;
        __syncthreads();
        const int b = row0 >> 8, kloc0 = row0 & 255;
        float* dstb = YkT + (size_t)b * HN * KN + kloc0;
#pragma unroll
        for (int i = 0; i < 16; ++i) {
            int idx = i * 256 + tid;
            int h_out = idx >> 4, kj = idx & 15;
            dstb[(size_t)h_out * KN + kj] = trans[kj][h_out];
        }
    }
}

// ------------- Kernel B (fused): score + masked softmax + PV ----------------
// Block = 256 threads = 4 waves = 4 consecutive q of one batch b.
// Wave = 1 q; lane owns k = kt*64 + lane per k-tile kt (0..3).
//   score: acc = sum_h wv[h]*rcp(1+exp2(qs[q][h]+ksT[h][k]))  (tanh identity;
//          softmax-invariant constant dropped). kv = b32 wave-load, 256B ALL UNIQUE;
//          qs/wv are wave-uniform LDS broadcasts. Whole k-tiles >= len skipped.
//   softmax: 4 regs/lane, wave shfl reduce (as before), p==0 exactly for k>=len.
//   PV: V staged in 16-row LDS tiles shared by all 4 waves (4x less V traffic);
//       lane owns 4 d columns; p broadcast from per-wave LDS row.
__global__ __launch_bounds__(256, 4) void attn_kernel(const float* __restrict__ QS,
                                                      const float* __restrict__ KT,
                                                      const float* __restrict__ wv,
                                                      const int* __restrict__ lens,
                                                      const float* __restrict__ V,
                                                      float* __restrict__ OUT) {
    const int b = blockIdx.y;
    const int q0 = blockIdx.x * 4;
    const int len = lens[b];

    __shared__ float qrow_lds[4][256];  // 4 KB
    __shared__ float wv_lds[256];       // 1 KB
    __shared__ float srow[4][256];      // 4 KB
    __shared__ float vtile[16][256];    // 16 KB

    const int tid = threadIdx.x;
    const int w = tid >> 6, lane = tid & 63;

    // stage q rows + wv (coalesced, once)
    {
        int wq = tid >> 6, c4 = (tid & 63) << 2;
        *(float4*)&qrow_lds[wq][c4] =
            *(const float4*)&QS[((size_t)b * QN + q0 + wq) * HN + c4];
        if (tid < 64) *(float4*)&wv_lds[tid << 2] = *(const float4*)&wv[tid << 2];
    }
    __syncthreads();

    const float* ktb = KT + (size_t)b * HN * KN;
    const float* qr = &qrow_lds[w][0];

    float xs0, xs1, xs2, xs3;
#pragma unroll
    for (int kt = 0; kt < 4; ++kt) {
        float a = 0.f;
        if (kt * 64 < len) {  // wave-uniform skip
            const float* kp = ktb + kt * 64 + lane;
#pragma unroll 2
            for (int h0 = 0; h0 < HN; h0 += 8) {
                float kv[8];
#pragma unroll
                for (int u = 0; u < 8; ++u) kv[u] = kp[(size_t)(h0 + u) * KN];
#pragma unroll
                for (int u = 0; u < 8; ++u) {
                    float qv = qr[h0 + u];       // broadcast
                    float wl = wv_lds[h0 + u];   // broadcast
                    float e = __builtin_amdgcn_exp2f(qv + kv[u]);
                    a = fmaf(wl, __builtin_amdgcn_rcpf(1.f + e), a);
                }
            }
        }
        float x = (kt * 64 + lane < len) ? (-2.f * a) : -1e6f;
        if (kt == 0) xs0 = x;
        else if (kt == 1) xs1 = x;
        else if (kt == 2) xs2 = x;
        else xs3 = x;
    }

    // wave softmax over 256 scores (4 regs/lane)
    float m = fmaxf(fmaxf(xs0, xs1), fmaxf(xs2, xs3));
#pragma unroll
    for (int off = 32; off; off >>= 1) m = fmaxf(m, __shfl_xor(m, off, 64));
    float p0 = __builtin_amdgcn_exp2f((xs0 - m) * LOG2E);
    float p1 = __builtin_amdgcn_exp2f((xs1 - m) * LOG2E);
    float p2 = __builtin_amdgcn_exp2f((xs2 - m) * LOG2E);
    float p3 = __builtin_amdgcn_exp2f((xs3 - m) * LOG2E);
    float s = (p0 + p1) + (p2 + p3);
#pragma unroll
    for (int off = 32; off; off >>= 1) s += __shfl_xor(s, off, 64);
    float inv = 1.f / s;
    srow[w][lane] = p0 * inv;
    srow[w][lane + 64] = p1 * inv;
    srow[w][lane + 128] = p2 * inv;
    srow[w][lane + 192] = p3 * inv;

    // PV with block-shared V tiles (16 k-rows each)
    const int nt = (len + 15) >> 4;
    float4 oa = make_float4(0.f, 0.f, 0.f, 0.f);
    const float* vb = V + (size_t)b * KN * DN;
    const int d4 = lane << 2;

    for (int t = 0; t < nt; ++t) {
        __syncthreads();  // protect vtile reuse + (first iter) srow visibility
        {
            int row = tid >> 4, c4 = (tid & 15) << 4;  // 16 rows x 4 float4 each
#pragma unroll
            for (int j = 0; j < 4; ++j)
                *(float4*)&vtile[row][c4 + 4 * j] =
                    *(const float4*)&vb[(size_t)(t * 16 + row) * DN + c4 + 4 * j];
        }
        __syncthreads();
#pragma unroll 4
        for (int kk = 0; kk < 16; ++kk) {
            float p = srow[w][t * 16 + kk];          // broadcast (0 beyond len)
            float4 v = *(const float4*)&vtile[kk][d4];
            oa.x = fmaf(p, v.x, oa.x);
            oa.y = fmaf(p, v.y, oa.y);
            oa.z = fmaf(p, v.z, oa.z);
            oa.w = fmaf(p, v.w, oa.w);
        }
    }

    *(float4*)&OUT[((size_t)b * QN + q0 + w) * DN + d4] = oa;
}

extern "C" void kernel_launch(void* const* d_in, const int* in_sizes, int n_in,
                              void* d_out, int out_size, void* d_ws, size_t ws_size,
                              hipStream_t stream) {
    const float* queries = (const float*)d_in[0];
    const float* keys    = (const float*)d_in[1];
    const float* values  = (const float*)d_in[2];
    const int*   lens    = (const int*)d_in[3];
    const float* Wq      = (const float*)d_in[4];
    const float* Wk      = (const float*)d_in[5];
    const float* wv      = (const float*)d_in[6];
    float* out = (float*)d_out;

    float* qs  = (float*)d_ws;                       // [B,Q,H]  4 MB (row-major)
    float* ksT = qs + (size_t)B_ * QN * HN;          // [B,H,K]  4 MB (transposed)

    proj_kernel<<<(B_ * QN + B_ * KN) / 16, 256, 0, stream>>>(
        queries, keys, Wq, Wk, qs, ksT, TWOLOG2E);

    dim3 gB(QN / 4, B_);
    attn_kernel<<<gB, 256, 0, stream>>>(qs, ksT, wv, lens, values, out);
}

// Round 8
// 72.186 us; speedup vs baseline: 1.7774x; 1.1840x over previous
//
#include <hip/hip_runtime.h>

#define B_ 16
#define QN 256
#define KN 256
#define DN 256
#define HN 256

#define LOG2E 1.4426950408889634f
#define TWOLOG2E 2.8853900817779268f  // exp2(x*this) = e^{2x}

__device__ inline float readlane_f(float v, int l) {
    return __uint_as_float(__builtin_amdgcn_readlane(__float_as_uint(v), l));
}

// ---------------- Kernel A (fused): projections ----------------
// 16 rows/block; thread = 4 rows x 4 h (16 FMA per LDS b128; x-row is wave-uniform ->
// broadcast, conflict-free). First half of grid: qs[b][q][h] row-major direct stores.
// Second half: ksT[b][h][k] via LDS transpose (64B-segmented global stores).
__global__ __launch_bounds__(256) void proj_kernel(const float* __restrict__ Xq,
                                                   const float* __restrict__ Xk,
                                                   const float* __restrict__ Wq,
                                                   const float* __restrict__ Wk,
                                                   float* __restrict__ Yq,
                                                   float* __restrict__ YkT,
                                                   float scale) {
    const int nb = (int)gridDim.x >> 1;
    int blk = blockIdx.x;
    const bool is_q = blk < nb;
    const float* X;
    const float* W;
    if (is_q) { X = Xq; W = Wq; }
    else      { X = Xk; W = Wk; blk -= nb; }
    const int row0 = blk * 16;

    __shared__ float xl[16][260];      // padded; rows uniform-broadcast anyway
    __shared__ float trans[16][260];   // k-path transpose buffer
    const int tid = threadIdx.x;

    {
        const float4* src = (const float4*)(X + (size_t)row0 * DN);
#pragma unroll
        for (int i = 0; i < 4; ++i) {
            int idx = tid + 256 * i;           // float4 index within 16x256
            int r = idx >> 6, c = (idx & 63) << 2;
            *(float4*)&xl[r][c] = src[idx];
        }
    }
    __syncthreads();

    const int rg = tid >> 6;          // wave id: rows rg*4 .. rg*4+3
    const int h4 = (tid & 63) << 2;   // 4 h columns

    float4 acc[4];
#pragma unroll
    for (int r = 0; r < 4; ++r) acc[r] = make_float4(0.f, 0.f, 0.f, 0.f);

    for (int d0 = 0; d0 < DN; d0 += 4) {
        float4 w[4];
#pragma unroll
        for (int j = 0; j < 4; ++j)
            w[j] = *(const float4*)&W[(size_t)(d0 + j) * HN + h4];  // coalesced 1KB
        float4 x[4];
#pragma unroll
        for (int r = 0; r < 4; ++r)
            x[r] = *(const float4*)&xl[(rg << 2) + r][d0];          // wave-uniform bcast
#pragma unroll
        for (int r = 0; r < 4; ++r) {
            acc[r].x = fmaf(x[r].x, w[0].x, acc[r].x);
            acc[r].y = fmaf(x[r].x, w[0].y, acc[r].y);
            acc[r].z = fmaf(x[r].x, w[0].z, acc[r].z);
            acc[r].w = fmaf(x[r].x, w[0].w, acc[r].w);
            acc[r].x = fmaf(x[r].y, w[1].x, acc[r].x);
            acc[r].y = fmaf(x[r].y, w[1].y, acc[r].y);
            acc[r].z = fmaf(x[r].y, w[1].z, acc[r].z);
            acc[r].w = fmaf(x[r].y, w[1].w, acc[r].w);
            acc[r].x = fmaf(x[r].z, w[2].x, acc[r].x);
            acc[r].y = fmaf(x[r].z, w[2].y, acc[r].y);
            acc[r].z = fmaf(x[r].z, w[2].z, acc[r].z);
            acc[r].w = fmaf(x[r].z, w[2].w, acc[r].w);
            acc[r].x = fmaf(x[r].w, w[3].x, acc[r].x);
            acc[r].y = fmaf(x[r].w, w[3].y, acc[r].y);
            acc[r].z = fmaf(x[r].w, w[3].z, acc[r].z);
            acc[r].w = fmaf(x[r].w, w[3].w, acc[r].w);
        }
    }

    if (is_q) {
#pragma unroll
        for (int r = 0; r < 4; ++r) {
            float4 o = make_float4(acc[r].x * scale, acc[r].y * scale,
                                   acc[r].z * scale, acc[r].w * scale);
            *(float4*)&Yq[(size_t)(row0 + (rg << 2) + r) * HN + h4] = o;
        }
    } else {
#pragma unroll
        for (int r = 0; r < 4; ++r) {
            float4 o = make_float4(acc[r].x * scale, acc[r].y * scale,
                                   acc[r].z * scale, acc[r].w * scale);
            *(float4*)&trans[(rg << 2) + r][h4] = o;   // uniform row, dense cols
        }
        __syncthreads();
        const int b = row0 >> 8, kloc0 = row0 & 255;
        float* dstb = YkT + (size_t)b * HN * KN + kloc0;
#pragma unroll
        for (int i = 0; i < 16; ++i) {
            int idx = i * 256 + tid;
            int h_out = idx >> 4, kj = idx & 15;
            dstb[(size_t)h_out * KN + kj] = trans[kj][h_out];  // 64B global segments
        }
    }
}

// ------------- Kernel B (fused): score + masked softmax + PV ----------------
// Block = 256 threads = 4 waves = 4 q. Wave = 1 q; lane owns k = 64*kt + lane.
// score: NO LDS -- kv per-lane b32 global (256B unique/wave-load); q/wv through
//        wave-uniform pointers (scalar/L1 path). tanh identity, softmax-invariant
//        constant dropped. Whole 64-k groups beyond len skipped (block-uniform).
// softmax: 4 regs/lane, shfl_xor wave reduce; masked p == 0 exactly.
// PV: p broadcast via v_readlane (static lane idx); V staged in flat 16KB LDS tiles
//     (dense conflict-free copy) shared by the 4 waves.
__global__ __launch_bounds__(256, 4) void attn_kernel(const float* __restrict__ QS,
                                                      const float* __restrict__ KT,
                                                      const float* __restrict__ wv,
                                                      const int* __restrict__ lens,
                                                      const float* __restrict__ V,
                                                      float* __restrict__ OUT) {
    const int b = blockIdx.y;
    const int q0 = blockIdx.x * 4;
    const int len = lens[b];

    __shared__ float vtile[16 * 256];   // 16 KB

    const int tid = threadIdx.x;
    const int w = tid >> 6, lane = tid & 63;
    const int wq = __builtin_amdgcn_readfirstlane(w);

    const float* qr = QS + ((size_t)b * QN + q0 + wq) * HN;  // wave-uniform pointer
    const float* ktb = KT + (size_t)b * HN * KN;

    float xs[4];
#pragma unroll
    for (int kt = 0; kt < 4; ++kt) {
        float a = 0.f;
        if (kt * 64 < len) {   // block-uniform skip
            const float* kp = ktb + kt * 64 + lane;
#pragma unroll 2
            for (int h0 = 0; h0 < HN; h0 += 8) {
                float kv[8];
#pragma unroll
                for (int u = 0; u < 8; ++u) kv[u] = kp[(size_t)(h0 + u) * KN];
                float4 qa = *(const float4*)&qr[h0];
                float4 qb = *(const float4*)&qr[h0 + 4];
                float4 wa = *(const float4*)&wv[h0];
                float4 wb = *(const float4*)&wv[h0 + 4];
                float qv[8] = {qa.x, qa.y, qa.z, qa.w, qb.x, qb.y, qb.z, qb.w};
                float wl[8] = {wa.x, wa.y, wa.z, wa.w, wb.x, wb.y, wb.z, wb.w};
#pragma unroll
                for (int u = 0; u < 8; ++u) {
                    float e = __builtin_amdgcn_exp2f(qv[u] + kv[u]);
                    a = fmaf(wl[u], __builtin_amdgcn_rcpf(1.f + e), a);
                }
            }
        }
        xs[kt] = (kt * 64 + lane < len) ? (-2.f * a) : -1e6f;
    }

    // wave softmax over 256 scores held in 4 regs/lane
    float m = fmaxf(fmaxf(xs[0], xs[1]), fmaxf(xs[2], xs[3]));
#pragma unroll
    for (int off = 32; off; off >>= 1) m = fmaxf(m, __shfl_xor(m, off, 64));
    float p0 = __builtin_amdgcn_exp2f((xs[0] - m) * LOG2E);
    float p1 = __builtin_amdgcn_exp2f((xs[1] - m) * LOG2E);
    float p2 = __builtin_amdgcn_exp2f((xs[2] - m) * LOG2E);
    float p3 = __builtin_amdgcn_exp2f((xs[3] - m) * LOG2E);
    float s = (p0 + p1) + (p2 + p3);
#pragma unroll
    for (int off = 32; off; off >>= 1) s += __shfl_xor(s, off, 64);
    float inv = 1.f / s;
    p0 *= inv; p1 *= inv; p2 *= inv; p3 *= inv;

    // PV: 64-k groups; within a group, 4 tiles of 16 k staged in LDS (flat copy)
    const int ngrp = (len + 63) >> 6;
    float4 oa = make_float4(0.f, 0.f, 0.f, 0.f);
    const float* vb = V + (size_t)b * KN * DN;
    const int d4 = lane << 2;

#pragma unroll
    for (int kt = 0; kt < 4; ++kt) {
        if (kt >= ngrp) break;                // block-uniform
        float pk = (kt == 0) ? p0 : (kt == 1) ? p1 : (kt == 2) ? p2 : p3;
#pragma unroll
        for (int t2 = 0; t2 < 4; ++t2) {
            __syncthreads();
            {
                const float4* src = (const float4*)(vb + ((size_t)kt * 64 + t2 * 16) * DN);
                float4* dst = (float4*)vtile;
#pragma unroll
                for (int j = 0; j < 4; ++j) dst[tid + 256 * j] = src[tid + 256 * j];
            }
            __syncthreads();
#pragma unroll
            for (int kk = 0; kk < 16; ++kk) {
                float p = readlane_f(pk, t2 * 16 + kk);   // static lane index
                float4 v = *(const float4*)&vtile[kk * 256 + d4];
                oa.x = fmaf(p, v.x, oa.x);
                oa.y = fmaf(p, v.y, oa.y);
                oa.z = fmaf(p, v.z, oa.z);
                oa.w = fmaf(p, v.w, oa.w);
            }
        }
    }

    *(float4*)&OUT[((size_t)b * QN + q0 + w) * DN + d4] = oa;
}

extern "C" void kernel_launch(void* const* d_in, const int* in_sizes, int n_in,
                              void* d_out, int out_size, void* d_ws, size_t ws_size,
                              hipStream_t stream) {
    const float* queries = (const float*)d_in[0];
    const float* keys    = (const float*)d_in[1];
    const float* values  = (const float*)d_in[2];
    const int*   lens    = (const int*)d_in[3];
    const float* Wq      = (const float*)d_in[4];
    const float* Wk      = (const float*)d_in[5];
    const float* wv      = (const float*)d_in[6];
    float* out = (float*)d_out;

    float* qs  = (float*)d_ws;                       // [B,Q,H]  4 MB (row-major)
    float* ksT = qs + (size_t)B_ * QN * HN;          // [B,H,K]  4 MB (transposed)

    proj_kernel<<<(B_ * QN + B_ * KN) / 16, 256, 0, stream>>>(
        queries, keys, Wq, Wk, qs, ksT, TWOLOG2E);

    dim3 gB(QN / 4, B_);
    attn_kernel<<<gB, 256, 0, stream>>>(qs, ksT, wv, lens, values, out);
}

// Round 9
// 67.829 us; speedup vs baseline: 1.8915x; 1.0642x over previous
//
#include <hip/hip_runtime.h>

#define B_ 16
#define QN 256
#define KN 256
#define DN 256
#define HN 256

#define LOG2E 1.4426950408889634f
#define TWOLOG2E 2.8853900817779268f  // exp2(x*this) = e^{2x}

__device__ inline float readlane_f(float v, int l) {
    return __uint_as_float(__builtin_amdgcn_readlane(__float_as_uint(v), l));
}

// ---------------- Kernel A (fused): projections + exp ----------------
// 16 rows/block; thread = 4 rows x 4 h. Outputs are EXPONENTIALS of the scaled
// projections: eq = exp2(s*q@Wq), ek = exp2(s*k@Wk), s = 2*log2(e), so the score
// kernel needs no exp (e^{2(q+k)} = eq*ek).
// q-path: row-major direct stores. k-path: LDS transpose into [h/8][k][8] octet
// layout so the score kernel's window loads are 2x b128 per 8 h.
// W loads are 2-stage software-pipelined (prefetch d0+4 while computing d0).
__global__ __launch_bounds__(256) void proj_kernel(const float* __restrict__ Xq,
                                                   const float* __restrict__ Xk,
                                                   const float* __restrict__ Wq,
                                                   const float* __restrict__ Wk,
                                                   float* __restrict__ EQ,
                                                   float* __restrict__ EKT,
                                                   float scale) {
    const int nb = (int)gridDim.x >> 1;
    int blk = blockIdx.x;
    const bool is_q = blk < nb;
    const float* X;
    const float* W;
    if (is_q) { X = Xq; W = Wq; }
    else      { X = Xk; W = Wk; blk -= nb; }
    const int row0 = blk * 16;

    __shared__ float xl[16][260];
    __shared__ float trans[16][260];
    const int tid = threadIdx.x;

    {
        const float4* src = (const float4*)(X + (size_t)row0 * DN);
#pragma unroll
        for (int i = 0; i < 4; ++i) {
            int idx = tid + 256 * i;
            int r = idx >> 6, c = (idx & 63) << 2;
            *(float4*)&xl[r][c] = src[idx];
        }
    }
    __syncthreads();

    const int rg = tid >> 6;          // wave id: rows rg*4 .. rg*4+3
    const int h4 = (tid & 63) << 2;   // 4 h columns

    float4 acc[4];
#pragma unroll
    for (int r = 0; r < 4; ++r) acc[r] = make_float4(0.f, 0.f, 0.f, 0.f);

    float4 wb0[4], wb1[4];
#pragma unroll
    for (int j = 0; j < 4; ++j) wb0[j] = *(const float4*)&W[(size_t)j * HN + h4];

#define PROJ_COMP(WB, D0)                                                      \
    do {                                                                       \
        float4 x[4];                                                           \
        _Pragma("unroll") for (int r = 0; r < 4; ++r)                          \
            x[r] = *(const float4*)&xl[(rg << 2) + r][(D0)];                   \
        _Pragma("unroll") for (int r = 0; r < 4; ++r) {                        \
            acc[r].x = fmaf(x[r].x, WB[0].x, acc[r].x);                        \
            acc[r].y = fmaf(x[r].x, WB[0].y, acc[r].y);                        \
            acc[r].z = fmaf(x[r].x, WB[0].z, acc[r].z);                        \
            acc[r].w = fmaf(x[r].x, WB[0].w, acc[r].w);                        \
            acc[r].x = fmaf(x[r].y, WB[1].x, acc[r].x);                        \
            acc[r].y = fmaf(x[r].y, WB[1].y, acc[r].y);                        \
            acc[r].z = fmaf(x[r].y, WB[1].z, acc[r].z);                        \
            acc[r].w = fmaf(x[r].y, WB[1].w, acc[r].w);                        \
            acc[r].x = fmaf(x[r].z, WB[2].x, acc[r].x);                        \
            acc[r].y = fmaf(x[r].z, WB[2].y, acc[r].y);                        \
            acc[r].z = fmaf(x[r].z, WB[2].z, acc[r].z);                        \
            acc[r].w = fmaf(x[r].z, WB[2].w, acc[r].w);                        \
            acc[r].x = fmaf(x[r].w, WB[3].x, acc[r].x);                        \
            acc[r].y = fmaf(x[r].w, WB[3].y, acc[r].y);                        \
            acc[r].z = fmaf(x[r].w, WB[3].z, acc[r].z);                        \
            acc[r].w = fmaf(x[r].w, WB[3].w, acc[r].w);                        \
        }                                                                      \
    } while (0)

    for (int d0 = 0; d0 < DN; d0 += 8) {
#pragma unroll
        for (int j = 0; j < 4; ++j)
            wb1[j] = *(const float4*)&W[(size_t)(d0 + 4 + j) * HN + h4];
        PROJ_COMP(wb0, d0);
        if (d0 + 8 < DN) {
#pragma unroll
            for (int j = 0; j < 4; ++j)
                wb0[j] = *(const float4*)&W[(size_t)(d0 + 8 + j) * HN + h4];
        }
        PROJ_COMP(wb1, d0 + 4);
    }

    // apply exp2(scale * acc)
#pragma unroll
    for (int r = 0; r < 4; ++r) {
        acc[r].x = __builtin_amdgcn_exp2f(acc[r].x * scale);
        acc[r].y = __builtin_amdgcn_exp2f(acc[r].y * scale);
        acc[r].z = __builtin_amdgcn_exp2f(acc[r].z * scale);
        acc[r].w = __builtin_amdgcn_exp2f(acc[r].w * scale);
    }

    if (is_q) {
#pragma unroll
        for (int r = 0; r < 4; ++r)
            *(float4*)&EQ[(size_t)(row0 + (rg << 2) + r) * HN + h4] = acc[r];
    } else {
#pragma unroll
        for (int r = 0; r < 4; ++r)
            *(float4*)&trans[(rg << 2) + r][h4] = acc[r];
        __syncthreads();
        const int b = row0 >> 8, kloc0 = row0 & 255;
        float* dstb = EKT + (size_t)b * 32 * 256 * 8;
        // [h0][k][u] layout, coalesced stores
#pragma unroll
        for (int i = 0; i < 4; ++i) {
            int idx = i * 256 + tid;          // float4 index, 0..1023
            int u4 = (idx & 1) << 2;
            int kj = (idx >> 1) & 15;
            int h0 = idx >> 5;                // 0..31
            float4 val = *(const float4*)&trans[kj][h0 * 8 + u4];
            *(float4*)&dstb[((size_t)h0 * 256 + kloc0 + kj) * 8 + u4] = val;
        }
    }
}

// ------------- Kernel B (fused): score + masked softmax + PV ----------------
// Block = 4 waves = 4 q. Wave = 1 q; lane owns k = 64*kt + lane.
// score: term = wv[h] * rcp(1 + eq[h]*ek[h][k]); no exp in the loop (split identity).
//   ek loads: 2x b128 per 8-h window ([h/8][k][8] octet layout); eq/wv via
//   wave-uniform pointers (scalar path). 2-stage software pipeline.
// softmax: 4 regs/lane, shfl_xor wave reduce; masked p == 0 exactly.
// PV: p broadcast via v_readlane; V staged in flat 16KB LDS tiles (conflict-free).
__global__ __launch_bounds__(256, 4) void attn_kernel(const float* __restrict__ EQ,
                                                      const float* __restrict__ EKT,
                                                      const float* __restrict__ wv,
                                                      const int* __restrict__ lens,
                                                      const float* __restrict__ V,
                                                      float* __restrict__ OUT) {
    const int b = blockIdx.y;
    const int q0 = blockIdx.x * 4;
    const int len = lens[b];

    __shared__ float vtile[16 * 256];   // 16 KB

    const int tid = threadIdx.x;
    const int w = tid >> 6, lane = tid & 63;
    const int wq = __builtin_amdgcn_readfirstlane(w);

    const float* qr = EQ + ((size_t)b * QN + q0 + wq) * HN;   // wave-uniform
    const float* ekb = EKT + (size_t)b * 32 * 256 * 8;

#define SCORE_COMP(KA, KB, QA, QB, WA, WB)                                        \
    do {                                                                          \
        a = fmaf(WA.x, __builtin_amdgcn_rcpf(fmaf(QA.x, KA.x, 1.f)), a);          \
        a = fmaf(WA.y, __builtin_amdgcn_rcpf(fmaf(QA.y, KA.y, 1.f)), a);          \
        a = fmaf(WA.z, __builtin_amdgcn_rcpf(fmaf(QA.z, KA.z, 1.f)), a);          \
        a = fmaf(WA.w, __builtin_amdgcn_rcpf(fmaf(QA.w, KA.w, 1.f)), a);          \
        a = fmaf(WB.x, __builtin_amdgcn_rcpf(fmaf(QB.x, KB.x, 1.f)), a);          \
        a = fmaf(WB.y, __builtin_amdgcn_rcpf(fmaf(QB.y, KB.y, 1.f)), a);          \
        a = fmaf(WB.z, __builtin_amdgcn_rcpf(fmaf(QB.z, KB.z, 1.f)), a);          \
        a = fmaf(WB.w, __builtin_amdgcn_rcpf(fmaf(QB.w, KB.w, 1.f)), a);          \
    } while (0)

    float xs[4];
#pragma unroll
    for (int kt = 0; kt < 4; ++kt) {
        float a = 0.f;
        if (kt * 64 < len) {   // block-uniform skip
            const float* kp = ekb + (size_t)(kt * 64 + lane) * 8;
            float4 k0a = *(const float4*)&kp[0];
            float4 k0b = *(const float4*)&kp[4];
            float4 q0a = *(const float4*)&qr[0], q0b = *(const float4*)&qr[4];
            float4 w0a = *(const float4*)&wv[0], w0b = *(const float4*)&wv[4];
            float4 k1a, k1b, q1a, q1b, w1a, w1b;
            for (int hw = 0; hw < 32; hw += 2) {
                const float* kp1 = kp + (size_t)(hw + 1) * 2048;
                k1a = *(const float4*)&kp1[0];
                k1b = *(const float4*)&kp1[4];
                q1a = *(const float4*)&qr[(hw + 1) * 8];
                q1b = *(const float4*)&qr[(hw + 1) * 8 + 4];
                w1a = *(const float4*)&wv[(hw + 1) * 8];
                w1b = *(const float4*)&wv[(hw + 1) * 8 + 4];
                SCORE_COMP(k0a, k0b, q0a, q0b, w0a, w0b);
                if (hw + 2 < 32) {
                    const float* kp0 = kp + (size_t)(hw + 2) * 2048;
                    k0a = *(const float4*)&kp0[0];
                    k0b = *(const float4*)&kp0[4];
                    q0a = *(const float4*)&qr[(hw + 2) * 8];
                    q0b = *(const float4*)&qr[(hw + 2) * 8 + 4];
                    w0a = *(const float4*)&wv[(hw + 2) * 8];
                    w0b = *(const float4*)&wv[(hw + 2) * 8 + 4];
                }
                SCORE_COMP(k1a, k1b, q1a, q1b, w1a, w1b);
            }
        }
        xs[kt] = (kt * 64 + lane < len) ? (-2.f * a) : -1e6f;
    }

    // wave softmax over 256 scores held in 4 regs/lane
    float m = fmaxf(fmaxf(xs[0], xs[1]), fmaxf(xs[2], xs[3]));
#pragma unroll
    for (int off = 32; off; off >>= 1) m = fmaxf(m, __shfl_xor(m, off, 64));
    float p0 = __builtin_amdgcn_exp2f((xs[0] - m) * LOG2E);
    float p1 = __builtin_amdgcn_exp2f((xs[1] - m) * LOG2E);
    float p2 = __builtin_amdgcn_exp2f((xs[2] - m) * LOG2E);
    float p3 = __builtin_amdgcn_exp2f((xs[3] - m) * LOG2E);
    float s = (p0 + p1) + (p2 + p3);
#pragma unroll
    for (int off = 32; off; off >>= 1) s += __shfl_xor(s, off, 64);
    float inv = 1.f / s;
    p0 *= inv; p1 *= inv; p2 *= inv; p3 *= inv;

    // PV: 64-k groups; within a group, 4 tiles of 16 k staged in LDS (flat copy)
    const int ngrp = (len + 63) >> 6;
    float4 oa = make_float4(0.f, 0.f, 0.f, 0.f);
    const float* vb = V + (size_t)b * KN * DN;
    const int d4 = lane << 2;

#pragma unroll
    for (int kt = 0; kt < 4; ++kt) {
        if (kt >= ngrp) break;                // block-uniform
        float pk = (kt == 0) ? p0 : (kt == 1) ? p1 : (kt == 2) ? p2 : p3;
#pragma unroll
        for (int t2 = 0; t2 < 4; ++t2) {
            __syncthreads();
            {
                const float4* src = (const float4*)(vb + ((size_t)kt * 64 + t2 * 16) * DN);
                float4* dst = (float4*)vtile;
#pragma unroll
                for (int j = 0; j < 4; ++j) dst[tid + 256 * j] = src[tid + 256 * j];
            }
            __syncthreads();
#pragma unroll
            for (int kk = 0; kk < 16; ++kk) {
                float p = readlane_f(pk, t2 * 16 + kk);   // static lane index
                float4 v = *(const float4*)&vtile[kk * 256 + d4];
                oa.x = fmaf(p, v.x, oa.x);
                oa.y = fmaf(p, v.y, oa.y);
                oa.z = fmaf(p, v.z, oa.z);
                oa.w = fmaf(p, v.w, oa.w);
            }
        }
    }

    *(float4*)&OUT[((size_t)b * QN + q0 + w) * DN + d4] = oa;
}

extern "C" void kernel_launch(void* const* d_in, const int* in_sizes, int n_in,
                              void* d_out, int out_size, void* d_ws, size_t ws_size,
                              hipStream_t stream) {
    const float* queries = (const float*)d_in[0];
    const float* keys    = (const float*)d_in[1];
    const float* values  = (const float*)d_in[2];
    const int*   lens    = (const int*)d_in[3];
    const float* Wq      = (const float*)d_in[4];
    const float* Wk      = (const float*)d_in[5];
    const float* wv      = (const float*)d_in[6];
    float* out = (float*)d_out;

    float* eq  = (float*)d_ws;                       // [B,Q,H]   4 MB (exp'd, row-major)
    float* ekT = eq + (size_t)B_ * QN * HN;          // [B,32,K,8] 4 MB (exp'd, octets)

    proj_kernel<<<(B_ * QN + B_ * KN) / 16, 256, 0, stream>>>(
        queries, keys, Wq, Wk, eq, ekT, TWOLOG2E);

    dim3 gB(QN / 4, B_);
    attn_kernel<<<gB, 256, 0, stream>>>(eq, ekT, wv, lens, values, out);
}